// Round 1
// baseline (348.186 us; speedup 1.0000x reference)
//
#include <hip/hip_runtime.h>
#include <hip/hip_bf16.h>
#include <cstdint>
#include <cstddef>

#define DEVINL __device__ __forceinline__

typedef __attribute__((ext_vector_type(4))) float   f32x4;
typedef __bf16 bf16x8 __attribute__((ext_vector_type(8)));
typedef __attribute__((ext_vector_type(4))) short   short4v;
typedef __attribute__((ext_vector_type(4))) float   float4v;

static constexpr int BM = 128, BN = 128, BK = 32;
static constexpr int DIM = 1024;
static constexpr int NTOK = 4096;          // N1 == N2 == 4096

// ---------- scalar helpers ----------
DEVINL unsigned short f2bf(float f) {      // fp32 -> bf16 bits, RNE
  unsigned u = __float_as_uint(f);
  u += 0x7FFF + ((u >> 16) & 1);
  return (unsigned short)(u >> 16);
}
DEVINL float bf2f(unsigned short s) {
  return __uint_as_float(((unsigned)s) << 16);
}

// async global->LDS, 16B per lane. LDS dest must be wave-uniform base (+lane*16 implicit).
DEVINL void gll16(const void* g, void* l) {
  __builtin_amdgcn_global_load_lds(
      (const __attribute__((address_space(1))) void*)g,
      (__attribute__((address_space(3))) void*)l, 16, 0, 0);
}

// ---------- GEMM core: C[brow*128.., bcol*128..] = A * B^T  (both A,B K-major, ld == K) ----------
// 4 waves (2x2), each wave owns 64x64 = 4x4 fragments of 16x16x32 bf16 MFMA.
DEVINL void gemm_core(const unsigned short* __restrict__ A,
                      const unsigned short* __restrict__ B,
                      int K, int brow, int bcol,
                      f32x4 acc[4][4],
                      unsigned short* As, unsigned short* Bs)
{
  const int t = threadIdx.x;
  const int wave = t >> 6, lane = t & 63;
  const int wr = wave >> 1, wc = wave & 1;
  const int frow = lane & 15;          // fragment row (A) / col (B)
  const int kq = (lane >> 4) * 8;      // k-offset within 32
  const int sr = lane >> 2;            // staging row within a wave's 16-row chunk
  const int sc = (lane & 3) * 8;       // staging col (elements)

  const unsigned short* Abase = A + (size_t)(brow * BM) * K;
  const unsigned short* Bbase = B + (size_t)(bcol * BN) * K;

  for (int k0 = 0; k0 < K; k0 += BK) {
#pragma unroll
    for (int r = 0; r < 2; ++r) {
      const int rb = (r * 4 + wave) * 16;   // wave-uniform row base of 16-row chunk
      gll16(Abase + (size_t)(rb + sr) * K + k0 + sc, As + rb * BK);
      gll16(Bbase + (size_t)(rb + sr) * K + k0 + sc, Bs + rb * BK);
    }
    asm volatile("s_waitcnt vmcnt(0)" ::: "memory");
    __syncthreads();

    bf16x8 af[4], bfv[4];
#pragma unroll
    for (int m = 0; m < 4; ++m)
      af[m] = *(const bf16x8*)(As + (wr * 64 + m * 16 + frow) * BK + kq);
#pragma unroll
    for (int n = 0; n < 4; ++n)
      bfv[n] = *(const bf16x8*)(Bs + (wc * 64 + n * 16 + frow) * BK + kq);

#pragma unroll
    for (int m = 0; m < 4; ++m)
#pragma unroll
      for (int n = 0; n < 4; ++n)
        acc[m][n] = __builtin_amdgcn_mfma_f32_16x16x32_bf16(af[m], bfv[n], acc[m][n], 0, 0, 0);
    __syncthreads();
  }
}

DEVINL void zero_acc(f32x4 acc[4][4]) {
#pragma unroll
  for (int m = 0; m < 4; ++m)
#pragma unroll
    for (int n = 0; n < 4; ++n) {
      f32x4 z = {0.f, 0.f, 0.f, 0.f};
      acc[m][n] = z;
    }
}

// ---------- generic NT GEMM kernel ----------
// MODE 0: out = bf16( acc * scale ), row-major [M x N], ldo = N   (scores)
// MODE 1: out = f32 ( acc * scale ), row-major [M x N], ldo = N   (PV / context)
template <int MODE>
__global__ __launch_bounds__(256, 2)
void gemm_nt(const unsigned short* __restrict__ A, const unsigned short* __restrict__ B,
             void* __restrict__ Out, int K, int ldo, float scale)
{
  __shared__ unsigned short As[BM * BK];
  __shared__ unsigned short Bs[BN * BK];
  f32x4 acc[4][4];
  zero_acc(acc);
  gemm_core(A, B, K, blockIdx.y, blockIdx.x, acc, As, Bs);

  const int t = threadIdx.x, wave = t >> 6, lane = t & 63;
  const int wr = wave >> 1, wc = wave & 1;
  const int rr = (lane >> 4) * 4, cc = lane & 15;
#pragma unroll
  for (int m = 0; m < 4; ++m) {
    const int row0 = blockIdx.y * BM + wr * 64 + m * 16 + rr;
#pragma unroll
    for (int n = 0; n < 4; ++n) {
      const int col = blockIdx.x * BN + wc * 64 + n * 16 + cc;
#pragma unroll
      for (int i = 0; i < 4; ++i) {
        const float v = acc[m][n][i] * scale;
        if constexpr (MODE == 0)
          ((unsigned short*)Out)[(size_t)(row0 + i) * ldo + col] = f2bf(v);
        else
          ((float*)Out)[(size_t)(row0 + i) * ldo + col] = v;
      }
    }
  }
}

// ---------- merged QKV GEMM: grid.z = 6 (q1,k1,v1,q2,k2,v2); v outputs stored transposed ----------
__global__ __launch_bounds__(256, 2)
void qkv_gemm(const unsigned short* __restrict__ x1, const unsigned short* __restrict__ x2,
              const unsigned short* __restrict__ W6,
              const float* bq1, const float* bk1, const float* bv1,
              const float* bq2, const float* bk2, const float* bv2,
              unsigned short* q1, unsigned short* k1, unsigned short* v1T,
              unsigned short* q2, unsigned short* k2, unsigned short* v2T)
{
  __shared__ unsigned short As[BM * BK];
  __shared__ unsigned short Bs[BN * BK];
  const int g = blockIdx.z;
  const unsigned short* A = (g < 3) ? x1 : x2;
  const unsigned short* W = W6 + (size_t)g * (DIM * DIM);
  const float* bias = (g == 0) ? bq1 : (g == 1) ? bk1 : (g == 2) ? bv1
                    : (g == 3) ? bq2 : (g == 4) ? bk2 : bv2;
  unsigned short* out = (g == 0) ? q1 : (g == 1) ? k1 : (g == 2) ? v1T
                      : (g == 3) ? q2 : (g == 4) ? k2 : v2T;
  const bool vT = (g == 2 || g == 5);

  f32x4 acc[4][4];
  zero_acc(acc);
  gemm_core(A, W, DIM, blockIdx.y, blockIdx.x, acc, As, Bs);

  const int t = threadIdx.x, wave = t >> 6, lane = t & 63;
  const int wr = wave >> 1, wc = wave & 1;
  const int rr = (lane >> 4) * 4, cc = lane & 15;

  if (!vT) {
#pragma unroll
    for (int m = 0; m < 4; ++m) {
      const int row0 = blockIdx.y * BM + wr * 64 + m * 16 + rr;
#pragma unroll
      for (int n = 0; n < 4; ++n) {
        const int col = blockIdx.x * BN + wc * 64 + n * 16 + cc;
        const float b = bias[col];
#pragma unroll
        for (int i = 0; i < 4; ++i)
          out[(size_t)(row0 + i) * DIM + col] = f2bf(acc[m][n][i] + b);
      }
    }
  } else {
    // transposed store: vT[d][token], d = col, token rows consecutive per lane -> pack 4 bf16 (8B)
#pragma unroll
    for (int m = 0; m < 4; ++m) {
      const int row0 = blockIdx.y * BM + wr * 64 + m * 16 + rr;
#pragma unroll
      for (int n = 0; n < 4; ++n) {
        const int col = blockIdx.x * BN + wc * 64 + n * 16 + cc;
        const float b = bias[col];
        short4v pk;
#pragma unroll
        for (int i = 0; i < 4; ++i) pk[i] = (short)f2bf(acc[m][n][i] + b);
        *(short4v*)(out + (size_t)col * NTOK + row0) = pk;
      }
    }
  }
}

// ---------- row softmax, in place on bf16 [4096 x 4096] ----------
__global__ __launch_bounds__(256)
void softmax_inplace(unsigned short* __restrict__ S)
{
  const int row = blockIdx.x;
  unsigned short* r = S + (size_t)row * NTOK;
  const int t = threadIdx.x, wave = t >> 6, lane = t & 63;
  __shared__ float red[4];

  bf16x8 d0 = *(const bf16x8*)(r + t * 8);
  bf16x8 d1 = *(const bf16x8*)(r + 2048 + t * 8);
  float v[16];
  {
    const unsigned short* p0 = (const unsigned short*)&d0;
    const unsigned short* p1 = (const unsigned short*)&d1;
#pragma unroll
    for (int j = 0; j < 8; ++j) { v[j] = bf2f(p0[j]); v[8 + j] = bf2f(p1[j]); }
  }
  float mx = v[0];
#pragma unroll
  for (int j = 1; j < 16; ++j) mx = fmaxf(mx, v[j]);
#pragma unroll
  for (int o = 32; o > 0; o >>= 1) mx = fmaxf(mx, __shfl_xor(mx, o));
  if (lane == 0) red[wave] = mx;
  __syncthreads();
  mx = fmaxf(fmaxf(red[0], red[1]), fmaxf(red[2], red[3]));

  float s = 0.f;
#pragma unroll
  for (int j = 0; j < 16; ++j) { v[j] = __expf(v[j] - mx); s += v[j]; }
#pragma unroll
  for (int o = 32; o > 0; o >>= 1) s += __shfl_xor(s, o);
  __syncthreads();
  if (lane == 0) red[wave] = s;
  __syncthreads();
  s = red[0] + red[1] + red[2] + red[3];
  const float inv = 1.0f / s;

  unsigned short o0[8], o1[8];
#pragma unroll
  for (int j = 0; j < 8; ++j) { o0[j] = f2bf(v[j] * inv); o1[j] = f2bf(v[8 + j] * inv); }
  *(bf16x8*)(r + t * 8)        = *(const bf16x8*)o0;
  *(bf16x8*)(r + 2048 + t * 8) = *(const bf16x8*)o1;
}

// ---------- fp32 -> bf16 converters ----------
__global__ __launch_bounds__(256)
void cvt2(const float* __restrict__ a, const float* __restrict__ b,
          unsigned short* __restrict__ oa, unsigned short* __restrict__ ob)
{
  const float* in = blockIdx.y ? b : a;
  unsigned short* out = blockIdx.y ? ob : oa;
  const size_t i = ((size_t)blockIdx.x * 256 + threadIdx.x) * 4;
  float4v x = *(const float4v*)(in + i);
  short4v o;
#pragma unroll
  for (int j = 0; j < 4; ++j) o[j] = (short)f2bf(x[j]);
  *(short4v*)(out + i) = o;
}

__global__ __launch_bounds__(256)
void cvt_w(const float* w0, const float* w1, const float* w2,
           const float* w3, const float* w4, const float* w5,
           unsigned short* __restrict__ W6)
{
  const float* srcs[6] = {w0, w1, w2, w3, w4, w5};
  const float* in = srcs[blockIdx.y];
  unsigned short* out = W6 + (size_t)blockIdx.y * (DIM * DIM);
  const size_t i = ((size_t)blockIdx.x * 256 + threadIdx.x) * 4;
  float4v x = *(const float4v*)(in + i);
  short4v o;
#pragma unroll
  for (int j = 0; j < 4; ++j) o[j] = (short)f2bf(x[j]);
  *(short4v*)(out + i) = o;
}

// ---------- host launcher ----------
extern "C" void kernel_launch(void* const* d_in, const int* in_sizes, int n_in,
                              void* d_out, int out_size, void* d_ws, size_t ws_size,
                              hipStream_t stream)
{
  const float* x1  = (const float*)d_in[0];
  const float* x2  = (const float*)d_in[1];
  const float* Wq1 = (const float*)d_in[2];  const float* bq1 = (const float*)d_in[3];
  const float* Wk1 = (const float*)d_in[4];  const float* bk1 = (const float*)d_in[5];
  const float* Wv1 = (const float*)d_in[6];  const float* bv1 = (const float*)d_in[7];
  const float* Wq2 = (const float*)d_in[8];  const float* bq2 = (const float*)d_in[9];
  const float* Wk2 = (const float*)d_in[10]; const float* bk2 = (const float*)d_in[11];
  const float* Wv2 = (const float*)d_in[12]; const float* bv2 = (const float*)d_in[13];
  float* out = (float*)d_out;

  // workspace layout (elements of unsigned short / bf16):
  //   x1b(4M) x2b(4M) W6(6M) q1(4M) k1(4M) v1T(4M) q2(4M) k2(4M) v2T(4M) S(16M)  = 108 MB
  unsigned short* ws  = (unsigned short*)d_ws;
  const size_t NTD = (size_t)NTOK * DIM;           // 4M elems
  unsigned short* x1b = ws;
  unsigned short* x2b = x1b + NTD;
  unsigned short* W6  = x2b + NTD;
  unsigned short* q1  = W6 + 6 * (size_t)(DIM * DIM);
  unsigned short* k1  = q1 + NTD;
  unsigned short* v1T = k1 + NTD;
  unsigned short* q2  = v1T + NTD;
  unsigned short* k2  = q2 + NTD;
  unsigned short* v2T = k2 + NTD;
  unsigned short* S   = v2T + NTD;                 // 4096*4096 bf16

  const dim3 blk(256);
  cvt2 <<<dim3(NTD / 1024, 2), blk, 0, stream>>>(x1, x2, x1b, x2b);
  cvt_w<<<dim3((DIM * DIM) / 1024, 6), blk, 0, stream>>>(Wq1, Wk1, Wv1, Wq2, Wk2, Wv2, W6);

  qkv_gemm<<<dim3(DIM / BN, NTOK / BM, 6), blk, 0, stream>>>(
      x1b, x2b, W6, bq1, bk1, bv1, bq2, bk2, bv2, q1, k1, v1T, q2, k2, v2T);

  const float scale = 0.03125f;  // 1/sqrt(1024)

  // context1 = softmax(q2 k1^T / 32) @ v1   -> out[0 .. 4M)
  gemm_nt<0><<<dim3(NTOK / BN, NTOK / BM), blk, 0, stream>>>(q2, k1, S, DIM, NTOK, scale);
  softmax_inplace<<<dim3(NTOK), blk, 0, stream>>>(S);
  gemm_nt<1><<<dim3(DIM / BN, NTOK / BM), blk, 0, stream>>>(S, v1T, out, NTOK, DIM, 1.0f);

  // context2 = softmax(q1 k2^T / 32) @ v2   -> out[4M .. 8M)
  gemm_nt<0><<<dim3(NTOK / BN, NTOK / BM), blk, 0, stream>>>(q1, k2, S, DIM, NTOK, scale);
  softmax_inplace<<<dim3(NTOK), blk, 0, stream>>>(S);
  gemm_nt<1><<<dim3(DIM / BN, NTOK / BM), blk, 0, stream>>>(S, v2T, out + NTD, NTOK, DIM, 1.0f);
}

// Round 2
// 308.904 us; speedup vs baseline: 1.1272x; 1.1272x over previous
//
#include <hip/hip_runtime.h>
#include <hip/hip_bf16.h>
#include <cstdint>
#include <cstddef>

#define DEVINL __device__ __forceinline__

typedef __attribute__((ext_vector_type(4))) float   f32x4;
typedef __bf16 bf16x8 __attribute__((ext_vector_type(8)));
typedef __attribute__((ext_vector_type(4))) short   short4v;
typedef __attribute__((ext_vector_type(4))) float   float4v;

static constexpr int BM = 128, BN = 128, BK = 32;
static constexpr int DIM = 1024;
static constexpr int NTOK = 4096;          // N1 == N2 == 4096

// ---------- scalar helpers ----------
DEVINL unsigned short f2bf(float f) {      // fp32 -> bf16 bits, RNE
  unsigned u = __float_as_uint(f);
  u += 0x7FFF + ((u >> 16) & 1);
  return (unsigned short)(u >> 16);
}
DEVINL float bf2f(unsigned short s) {
  return __uint_as_float(((unsigned)s) << 16);
}

// async global->LDS, 16B per lane. LDS dest is wave-uniform base (+lane*16 implicit).
DEVINL void gll16(const void* g, void* l) {
  __builtin_amdgcn_global_load_lds(
      (const __attribute__((address_space(1))) void*)g,
      (__attribute__((address_space(3))) void*)l, 16, 0, 0);
}

// ---------- GEMM core (double-buffered, 2-phase pipeline) ----------
// C[brow*128.., bcol*128..] += A[rows, kb:kb+klen] * B[rows, kb:kb+klen]^T
// A row stride = lda, B row stride = ldb. 4 waves (2x2), each wave 64x64 out
// as 4x4 fragments of 16x16x32 bf16 MFMA.
// lds must hold 4 * BM*BK ushorts (32 KB): As0 Bs0 As1 Bs1.
DEVINL void gemm_core(const unsigned short* __restrict__ A, int lda,
                      const unsigned short* __restrict__ B, int ldb,
                      int kb, int klen, int brow, int bcol,
                      f32x4 acc[4][4], unsigned short* lds)
{
  const int t = threadIdx.x;
  const int wave = t >> 6, lane = t & 63;
  const int wr = wave >> 1, wc = wave & 1;
  const int frow = lane & 15;          // fragment row (A) / col (B)
  const int kq = (lane >> 4) * 8;      // k-offset within 32
  const int sr = lane >> 2;            // staging row within a 16-row chunk
  const int sc = (lane & 3) * 8;       // staging col (elements)

  const unsigned short* Arow = A + (size_t)(brow * BM) * lda + kb;
  const unsigned short* Brow = B + (size_t)(bcol * BN) * ldb + kb;

  unsigned short* As0 = lds;
  unsigned short* Bs0 = lds + BM * BK;
  unsigned short* As1 = lds + 2 * BM * BK;
  unsigned short* Bs1 = lds + 3 * BM * BK;

#define STAGE(Asb, Bsb, k0)                                                   \
  {                                                                           \
    _Pragma("unroll")                                                         \
    for (int r = 0; r < 2; ++r) {                                             \
      const int rb = (r * 4 + wave) * 16;                                     \
      gll16(Arow + (size_t)(rb + sr) * lda + (k0) + sc, (Asb) + rb * BK);     \
      gll16(Brow + (size_t)(rb + sr) * ldb + (k0) + sc, (Bsb) + rb * BK);     \
    }                                                                         \
  }

  // prologue: fill buffer 0
  STAGE(As0, Bs0, 0);
  asm volatile("s_waitcnt vmcnt(0)" ::: "memory");
  __syncthreads();

  const int nt = klen / BK;
  for (int tile = 0; tile < nt; ++tile) {
    unsigned short* Ac = (tile & 1) ? As1 : As0;
    unsigned short* Bc = (tile & 1) ? Bs1 : Bs0;
    unsigned short* An = (tile & 1) ? As0 : As1;
    unsigned short* Bn = (tile & 1) ? Bs0 : Bs1;

    // issue NEXT tile's loads first — their latency hides under this tile's
    // ds_read + MFMA (plus cross-block TLP).
    if (tile + 1 < nt) STAGE(An, Bn, (tile + 1) * BK);

    bf16x8 af[4], bfv[4];
#pragma unroll
    for (int m = 0; m < 4; ++m)
      af[m] = *(const bf16x8*)(Ac + (wr * 64 + m * 16 + frow) * BK + kq);
#pragma unroll
    for (int n = 0; n < 4; ++n)
      bfv[n] = *(const bf16x8*)(Bc + (wc * 64 + n * 16 + frow) * BK + kq);

#pragma unroll
    for (int m = 0; m < 4; ++m)
#pragma unroll
      for (int n = 0; n < 4; ++n)
        acc[m][n] = __builtin_amdgcn_mfma_f32_16x16x32_bf16(af[m], bfv[n], acc[m][n], 0, 0, 0);

    // one drain + barrier per K-step: next tile's buffer is now ready, and
    // every wave is past its reads of the buffer we stage into next iter.
    asm volatile("s_waitcnt vmcnt(0)" ::: "memory");
    __syncthreads();
  }
#undef STAGE
}

DEVINL void zero_acc(f32x4 acc[4][4]) {
#pragma unroll
  for (int m = 0; m < 4; ++m)
#pragma unroll
    for (int n = 0; n < 4; ++n) {
      f32x4 z = {0.f, 0.f, 0.f, 0.f};
      acc[m][n] = z;
    }
}

// ---------- generic NT GEMM kernel ----------
// MODE 0: out = bf16( acc * scale ), row-major, ldo  (scores)
// MODE 1: out = f32 ( acc ),          row-major, ldo  (PV partials / context)
// blockIdx.z selects K-chunk: kb = z*klen; z>0 writes to Part instead of Out.
template <int MODE>
__global__ __launch_bounds__(256, 4)
void gemm_nt(const unsigned short* __restrict__ A, int lda,
             const unsigned short* __restrict__ B, int ldb,
             void* __restrict__ Out, void* __restrict__ Part,
             int klen, int ldo, float scale)
{
  __shared__ unsigned short lds[4 * BM * BK];
  f32x4 acc[4][4];
  zero_acc(acc);
  gemm_core(A, lda, B, ldb, blockIdx.z * klen, klen, blockIdx.y, blockIdx.x, acc, lds);

  void* dst = (blockIdx.z == 0) ? Out : Part;
  const int t = threadIdx.x, wave = t >> 6, lane = t & 63;
  const int wr = wave >> 1, wc = wave & 1;
  const int rr = (lane >> 4) * 4, cc = lane & 15;
#pragma unroll
  for (int m = 0; m < 4; ++m) {
    const int row0 = blockIdx.y * BM + wr * 64 + m * 16 + rr;
#pragma unroll
    for (int n = 0; n < 4; ++n) {
      const int col = blockIdx.x * BN + wc * 64 + n * 16 + cc;
#pragma unroll
      for (int i = 0; i < 4; ++i) {
        const float v = acc[m][n][i] * scale;
        if constexpr (MODE == 0)
          ((unsigned short*)dst)[(size_t)(row0 + i) * ldo + col] = f2bf(v);
        else
          ((float*)dst)[(size_t)(row0 + i) * ldo + col] = v;
      }
    }
  }
}

// out[i] += part[i], vectorized
__global__ __launch_bounds__(256)
void add_partial(float* __restrict__ out, const float* __restrict__ part, int n4)
{
  const int i = blockIdx.x * 256 + threadIdx.x;
  if (i < n4) {
    float4v a = ((const float4v*)out)[i];
    float4v b = ((const float4v*)part)[i];
#pragma unroll
    for (int j = 0; j < 4; ++j) a[j] += b[j];
    ((float4v*)out)[i] = a;
  }
}

// ---------- merged QKV GEMM: grid.z = 6 (q1,k1,v1,q2,k2,v2); v outputs transposed ----------
__global__ __launch_bounds__(256, 4)
void qkv_gemm(const unsigned short* __restrict__ x1, const unsigned short* __restrict__ x2,
              const unsigned short* __restrict__ W6,
              const float* bq1, const float* bk1, const float* bv1,
              const float* bq2, const float* bk2, const float* bv2,
              unsigned short* q1, unsigned short* k1, unsigned short* v1T,
              unsigned short* q2, unsigned short* k2, unsigned short* v2T)
{
  __shared__ unsigned short lds[4 * BM * BK];
  const int g = blockIdx.z;
  const unsigned short* A = (g < 3) ? x1 : x2;
  const unsigned short* W = W6 + (size_t)g * (DIM * DIM);
  const float* bias = (g == 0) ? bq1 : (g == 1) ? bk1 : (g == 2) ? bv1
                    : (g == 3) ? bq2 : (g == 4) ? bk2 : bv2;
  unsigned short* out = (g == 0) ? q1 : (g == 1) ? k1 : (g == 2) ? v1T
                      : (g == 3) ? q2 : (g == 4) ? k2 : v2T;
  const bool vT = (g == 2 || g == 5);

  f32x4 acc[4][4];
  zero_acc(acc);
  gemm_core(A, DIM, W, DIM, 0, DIM, blockIdx.y, blockIdx.x, acc, lds);

  const int t = threadIdx.x, wave = t >> 6, lane = t & 63;
  const int wr = wave >> 1, wc = wave & 1;
  const int rr = (lane >> 4) * 4, cc = lane & 15;

  if (!vT) {
#pragma unroll
    for (int m = 0; m < 4; ++m) {
      const int row0 = blockIdx.y * BM + wr * 64 + m * 16 + rr;
#pragma unroll
      for (int n = 0; n < 4; ++n) {
        const int col = blockIdx.x * BN + wc * 64 + n * 16 + cc;
        const float b = bias[col];
#pragma unroll
        for (int i = 0; i < 4; ++i)
          out[(size_t)(row0 + i) * DIM + col] = f2bf(acc[m][n][i] + b);
      }
    }
  } else {
    // transposed store: vT[d][token]; 4 consecutive tokens per lane -> 8B packed
#pragma unroll
    for (int m = 0; m < 4; ++m) {
      const int row0 = blockIdx.y * BM + wr * 64 + m * 16 + rr;
#pragma unroll
      for (int n = 0; n < 4; ++n) {
        const int col = blockIdx.x * BN + wc * 64 + n * 16 + cc;
        const float b = bias[col];
        short4v pk;
#pragma unroll
        for (int i = 0; i < 4; ++i) pk[i] = (short)f2bf(acc[m][n][i] + b);
        *(short4v*)(out + (size_t)col * NTOK + row0) = pk;
      }
    }
  }
}

// ---------- row softmax, in place on bf16 [4096 x 4096] ----------
__global__ __launch_bounds__(256)
void softmax_inplace(unsigned short* __restrict__ S)
{
  const int row = blockIdx.x;
  unsigned short* r = S + (size_t)row * NTOK;
  const int t = threadIdx.x, wave = t >> 6, lane = t & 63;
  __shared__ float red[4];

  bf16x8 d0 = *(const bf16x8*)(r + t * 8);
  bf16x8 d1 = *(const bf16x8*)(r + 2048 + t * 8);
  float v[16];
  {
    const unsigned short* p0 = (const unsigned short*)&d0;
    const unsigned short* p1 = (const unsigned short*)&d1;
#pragma unroll
    for (int j = 0; j < 8; ++j) { v[j] = bf2f(p0[j]); v[8 + j] = bf2f(p1[j]); }
  }
  float mx = v[0];
#pragma unroll
  for (int j = 1; j < 16; ++j) mx = fmaxf(mx, v[j]);
#pragma unroll
  for (int o = 32; o > 0; o >>= 1) mx = fmaxf(mx, __shfl_xor(mx, o));
  if (lane == 0) red[wave] = mx;
  __syncthreads();
  mx = fmaxf(fmaxf(red[0], red[1]), fmaxf(red[2], red[3]));

  float s = 0.f;
#pragma unroll
  for (int j = 0; j < 16; ++j) { v[j] = __expf(v[j] - mx); s += v[j]; }
#pragma unroll
  for (int o = 32; o > 0; o >>= 1) s += __shfl_xor(s, o);
  __syncthreads();
  if (lane == 0) red[wave] = s;
  __syncthreads();
  s = red[0] + red[1] + red[2] + red[3];
  const float inv = 1.0f / s;

  unsigned short o0[8], o1[8];
#pragma unroll
  for (int j = 0; j < 8; ++j) { o0[j] = f2bf(v[j] * inv); o1[j] = f2bf(v[8 + j] * inv); }
  *(bf16x8*)(r + t * 8)        = *(const bf16x8*)o0;
  *(bf16x8*)(r + 2048 + t * 8) = *(const bf16x8*)o1;
}

// ---------- fp32 -> bf16 converters ----------
__global__ __launch_bounds__(256)
void cvt2(const float* __restrict__ a, const float* __restrict__ b,
          unsigned short* __restrict__ oa, unsigned short* __restrict__ ob)
{
  const float* in = blockIdx.y ? b : a;
  unsigned short* out = blockIdx.y ? ob : oa;
  const size_t i = ((size_t)blockIdx.x * 256 + threadIdx.x) * 4;
  float4v x = *(const float4v*)(in + i);
  short4v o;
#pragma unroll
  for (int j = 0; j < 4; ++j) o[j] = (short)f2bf(x[j]);
  *(short4v*)(out + i) = o;
}

__global__ __launch_bounds__(256)
void cvt_w(const float* w0, const float* w1, const float* w2,
           const float* w3, const float* w4, const float* w5,
           unsigned short* __restrict__ W6)
{
  const float* srcs[6] = {w0, w1, w2, w3, w4, w5};
  const float* in = srcs[blockIdx.y];
  unsigned short* out = W6 + (size_t)blockIdx.y * (DIM * DIM);
  const size_t i = ((size_t)blockIdx.x * 256 + threadIdx.x) * 4;
  float4v x = *(const float4v*)(in + i);
  short4v o;
#pragma unroll
  for (int j = 0; j < 4; ++j) o[j] = (short)f2bf(x[j]);
  *(short4v*)(out + i) = o;
}

// ---------- host launcher ----------
extern "C" void kernel_launch(void* const* d_in, const int* in_sizes, int n_in,
                              void* d_out, int out_size, void* d_ws, size_t ws_size,
                              hipStream_t stream)
{
  const float* x1  = (const float*)d_in[0];
  const float* x2  = (const float*)d_in[1];
  const float* Wq1 = (const float*)d_in[2];  const float* bq1 = (const float*)d_in[3];
  const float* Wk1 = (const float*)d_in[4];  const float* bk1 = (const float*)d_in[5];
  const float* Wv1 = (const float*)d_in[6];  const float* bv1 = (const float*)d_in[7];
  const float* Wq2 = (const float*)d_in[8];  const float* bq2 = (const float*)d_in[9];
  const float* Wk2 = (const float*)d_in[10]; const float* bk2 = (const float*)d_in[11];
  const float* Wv2 = (const float*)d_in[12]; const float* bv2 = (const float*)d_in[13];
  float* out = (float*)d_out;

  // workspace layout (ushort elems):
  //   x1b(4M) x2b(4M) W6(6M) q1(4M) k1(4M) v1T(4M) q2(4M) k2(4M) v2T(4M) S(16M) = 108 MB
  // P1 (fp32 PV partial, 16 MB) aliases x1b+x2b, which are dead after qkv_gemm.
  unsigned short* ws  = (unsigned short*)d_ws;
  const size_t NTD = (size_t)NTOK * DIM;           // 4M elems
  unsigned short* x1b = ws;
  unsigned short* x2b = x1b + NTD;
  unsigned short* W6  = x2b + NTD;
  unsigned short* q1  = W6 + 6 * (size_t)(DIM * DIM);
  unsigned short* k1  = q1 + NTD;
  unsigned short* v1T = k1 + NTD;
  unsigned short* q2  = v1T + NTD;
  unsigned short* k2  = q2 + NTD;
  unsigned short* v2T = k2 + NTD;
  unsigned short* S   = v2T + NTD;                 // 4096*4096 bf16
  float* P1 = (float*)ws;                          // aliases x1b+x2b (16 MB)

  const dim3 blk(256);
  cvt2 <<<dim3(NTD / 1024, 2), blk, 0, stream>>>(x1, x2, x1b, x2b);
  cvt_w<<<dim3((DIM * DIM) / 1024, 6), blk, 0, stream>>>(Wq1, Wk1, Wv1, Wq2, Wk2, Wv2, W6);

  qkv_gemm<<<dim3(DIM / BN, NTOK / BM, 6), blk, 0, stream>>>(
      x1b, x2b, W6, bq1, bk1, bv1, bq2, bk2, bv2, q1, k1, v1T, q2, k2, v2T);

  const float scale = 0.03125f;  // 1/sqrt(1024)
  const int KH = NTOK / 2;       // split-K chunk for PV

  // context1 = softmax(q2 k1^T / 32) @ v1   -> out[0 .. 4M)
  gemm_nt<0><<<dim3(NTOK / BN, NTOK / BM, 1), blk, 0, stream>>>(q2, DIM, k1, DIM, S, S, DIM, NTOK, scale);
  softmax_inplace<<<dim3(NTOK), blk, 0, stream>>>(S);
  gemm_nt<1><<<dim3(DIM / BN, NTOK / BM, 2), blk, 0, stream>>>(S, NTOK, v1T, NTOK, out, P1, KH, DIM, 1.0f);
  add_partial<<<dim3((NTD / 4 + 255) / 256), blk, 0, stream>>>(out, P1, NTD / 4);

  // context2 = softmax(q1 k2^T / 32) @ v2   -> out[4M .. 8M)
  gemm_nt<0><<<dim3(NTOK / BN, NTOK / BM, 1), blk, 0, stream>>>(q1, DIM, k2, DIM, S, S, DIM, NTOK, scale);
  softmax_inplace<<<dim3(NTOK), blk, 0, stream>>>(S);
  gemm_nt<1><<<dim3(DIM / BN, NTOK / BM, 2), blk, 0, stream>>>(S, NTOK, v2T, NTOK, out + NTD, P1, KH, DIM, 1.0f);
  add_partial<<<dim3((NTD / 4 + 255) / 256), blk, 0, stream>>>(out + NTD, P1, NTD / 4);
}

// Round 3
// 287.900 us; speedup vs baseline: 1.2094x; 1.0730x over previous
//
#include <hip/hip_runtime.h>
#include <hip/hip_bf16.h>
#include <cstdint>
#include <cstddef>

#define DEVINL __device__ __forceinline__

typedef __attribute__((ext_vector_type(4))) float   f32x4;
typedef __bf16 bf16x8 __attribute__((ext_vector_type(8)));
typedef __attribute__((ext_vector_type(4))) short   short4v;
typedef __attribute__((ext_vector_type(4))) float   float4v;

static constexpr int BM = 128, BN = 128, BK = 32;   // old core (PV only)
static constexpr int DIM = 1024;
static constexpr int NTOK = 4096;

// ---------- scalar helpers ----------
DEVINL unsigned short f2bf(float f) {
  unsigned u = __float_as_uint(f);
  u += 0x7FFF + ((u >> 16) & 1);
  return (unsigned short)(u >> 16);
}
DEVINL float bf2f(unsigned short s) {
  return __uint_as_float(((unsigned)s) << 16);
}

DEVINL void gll16(const void* g, void* l) {
  __builtin_amdgcn_global_load_lds(
      (const __attribute__((address_space(1))) void*)g,
      (__attribute__((address_space(3))) void*)l, 16, 0, 0);
}

// =====================================================================
// 256x256x64 8-wave core, 4 phases/K-tile, counted vmcnt, T2 swizzle.
// A,B both K-major (NT GEMM), lda/ldb = K-stride. acc[8][4] f32x4.
// LDS: 128 KB = [A0 32K][B0 32K][A1 32K][B1 32K] (ushort units below).
// Swizzle: LDS[r][c] holds global elem c ^ ((r&7)<<3)  (involution).
// =====================================================================
DEVINL void core256(const unsigned short* __restrict__ A, int lda,
                    const unsigned short* __restrict__ B, int ldb,
                    int K, int brow, int bcol, f32x4 acc[8][4])
{
  __shared__ unsigned short lds[65536];   // 128 KB
  const int t = threadIdx.x;
  const int w = t >> 6, l = t & 63;
  const int wr = w >> 2, wc = w & 3;
  const int srow = l >> 3;
  const int scol = ((l & 7) ^ srow) << 3;            // inverse-swizzled source col
  const int l15 = l & 15;
  const int cs0 = (((l >> 4) << 3)      ^ ((l & 7) << 3));  // swizzled read col, ks=0
  const int cs1 = ((32 + ((l >> 4) << 3)) ^ ((l & 7) << 3)); // ks=1

  const unsigned short* aL = A + (size_t)(brow * 256 + srow) * lda + scol;
  const unsigned short* bL = B + (size_t)(bcol * 256 + srow) * ldb + scol;

#pragma unroll
  for (int m = 0; m < 8; ++m)
#pragma unroll
    for (int n = 0; n < 4; ++n) {
      f32x4 z = {0.f, 0.f, 0.f, 0.f};
      acc[m][n] = z;
    }

  // stage macros: one half = 2 x gll16 per thread (issue order defines vmcnt math)
#define STA_(Sbase, h, r, kt)                                                  \
  gll16(aL + (size_t)((r)*128 + (h)*64 + (w << 3)) * lda + (size_t)(kt)*64,    \
        (Sbase) + ((r)*128 + (h)*64 + (w << 3)) * 64)
#define STB_(Sbase, h, r, kt)                                                  \
  { const int g16_ = w + (r)*8;                                                \
    const int r0_ = (g16_ >> 2)*64 + (h)*32 + (g16_ & 3)*8;                    \
    gll16(bL + (size_t)r0_ * ldb + (size_t)(kt)*64, (Sbase) + r0_ * 64); }
#define LDA_(Abase, mh)                                                        \
  _Pragma("unroll")                                                            \
  for (int m4 = 0; m4 < 4; ++m4) {                                             \
    const unsigned short* p_ = (Abase) + (wr*128 + (mh)*64 + m4*16 + l15)*64;  \
    af[m4][0] = *(const bf16x8*)(p_ + cs0);                                    \
    af[m4][1] = *(const bf16x8*)(p_ + cs1);                                    \
  }
#define LDB_(Bbase, nh)                                                        \
  _Pragma("unroll")                                                            \
  for (int n2 = 0; n2 < 2; ++n2) {                                             \
    const unsigned short* p_ = (Bbase) + (wc*64 + (nh)*32 + n2*16 + l15)*64;   \
    bfr[n2][0] = *(const bf16x8*)(p_ + cs0);                                   \
    bfr[n2][1] = *(const bf16x8*)(p_ + cs1);                                   \
  }
#define MF_(mh, nh)                                                            \
  __builtin_amdgcn_s_setprio(1);                                               \
  _Pragma("unroll")                                                            \
  for (int m4 = 0; m4 < 4; ++m4)                                               \
  _Pragma("unroll")                                                            \
  for (int n2 = 0; n2 < 2; ++n2) {                                             \
    f32x4 c_ = acc[(mh)*4 + m4][(nh)*2 + n2];                                  \
    c_ = __builtin_amdgcn_mfma_f32_16x16x32_bf16(af[m4][0], bfr[n2][0], c_, 0,0,0); \
    c_ = __builtin_amdgcn_mfma_f32_16x16x32_bf16(af[m4][1], bfr[n2][1], c_, 0,0,0); \
    acc[(mh)*4 + m4][(nh)*2 + n2] = c_;                                        \
  }                                                                            \
  __builtin_amdgcn_s_setprio(0);
#define VMW4() asm volatile("s_waitcnt vmcnt(4)" ::: "memory")
#define VMW2() asm volatile("s_waitcnt vmcnt(2)" ::: "memory")
#define VMW0() asm volatile("s_waitcnt vmcnt(0)" ::: "memory")
#define LGW()  do { asm volatile("s_waitcnt lgkmcnt(0)" ::: "memory");         \
                    __builtin_amdgcn_sched_barrier(0); } while (0)
#define BARR() do { __builtin_amdgcn_s_barrier();                              \
                    asm volatile("" ::: "memory"); } while (0)

  // prologue: tile 0, halves in order A0,B0,A1,B1 (8 loads outstanding)
  {
    unsigned short* S0 = lds;
    STA_(S0, 0, 0, 0); STA_(S0, 0, 1, 0);
    STB_(S0 + 16384, 0, 0, 0); STB_(S0 + 16384, 0, 1, 0);
    STA_(S0, 1, 0, 0); STA_(S0, 1, 1, 0);
    STB_(S0 + 16384, 1, 0, 0); STB_(S0 + 16384, 1, 1, 0);
  }

  bf16x8 af[4][2], bfr[2][2];
  const int NT = K >> 6;
  for (int kt = 0; kt < NT - 1; ++kt) {
    const unsigned short* Ab = lds + (kt & 1) * 32768;
    const unsigned short* Bb = Ab + 16384;
    unsigned short* Sa = lds + ((kt & 1) ^ 1) * 32768;
    unsigned short* Sb = Sa + 16384;

    // p0: quadrant (m0,n0); needs A0,B0 (oldest 2 stage-ops) -> vmcnt(4)
    VMW4(); BARR();
    STA_(Sa, 0, 0, kt + 1); STA_(Sa, 0, 1, kt + 1);
    LDA_(Ab, 0); LDB_(Bb, 0);
    LGW(); MF_(0, 0);

    // p1: quadrant (m1,n0); needs A1 -> vmcnt(4)
    VMW4(); BARR();
    STB_(Sb, 0, 0, kt + 1); STB_(Sb, 0, 1, kt + 1);
    LDA_(Ab, 1);
    LGW(); MF_(1, 0);

    // p2: quadrant (m1,n1); needs B1 -> vmcnt(4)
    VMW4(); BARR();
    STA_(Sa, 1, 0, kt + 1); STA_(Sa, 1, 1, kt + 1);
    LDB_(Bb, 1);
    LGW(); MF_(1, 1);

    // p3: quadrant (m0,n1); A0,B1 already landed; no wait/barrier needed
    STB_(Sb, 1, 0, kt + 1); STB_(Sb, 1, 1, kt + 1);
    LDA_(Ab, 0);
    LGW(); MF_(0, 1);
  }

  // peeled last tile: no staging; drain 4 -> 2 -> 0
  {
    const int kt = NT - 1;
    const unsigned short* Ab = lds + (kt & 1) * 32768;
    const unsigned short* Bb = Ab + 16384;
    VMW4(); BARR();
    LDA_(Ab, 0); LDB_(Bb, 0);
    LGW(); MF_(0, 0);
    VMW2(); BARR();
    LDA_(Ab, 1);
    LGW(); MF_(1, 0);
    VMW0(); BARR();
    LDB_(Bb, 1);
    LGW(); MF_(1, 1);
    LDA_(Ab, 0);
    LGW(); MF_(0, 1);
  }
#undef STA_
#undef STB_
#undef LDA_
#undef LDB_
#undef MF_
#undef VMW4
#undef VMW2
#undef VMW0
#undef LGW
#undef BARR
}

// ---------- scores: S = bf16( (A B^T) * scale ), [4096 x 4096] ----------
__global__ __launch_bounds__(512, 2)
void gemm256_scores(const unsigned short* __restrict__ A,
                    const unsigned short* __restrict__ B,
                    unsigned short* __restrict__ S, float scale)
{
  f32x4 acc[8][4];
  core256(A, DIM, B, DIM, DIM, blockIdx.y, blockIdx.x, acc);

  const int t = threadIdx.x, w = t >> 6, l = t & 63;
  const int wr = w >> 2, wc = w & 3;
  const int r4 = (l >> 4) * 4, c = l & 15;
  const int row0 = blockIdx.y * 256 + wr * 128;
  const int col0 = blockIdx.x * 256 + wc * 64;
#pragma unroll
  for (int mf = 0; mf < 8; ++mf)
#pragma unroll
    for (int nf = 0; nf < 4; ++nf)
#pragma unroll
      for (int i = 0; i < 4; ++i)
        S[(size_t)(row0 + mf*16 + r4 + i) * NTOK + col0 + nf*16 + c] =
            f2bf(acc[mf][nf][i] * scale);
}

// ---------- merged QKV on 256-core: grid.z = 6; v outputs transposed ----------
__global__ __launch_bounds__(512, 2)
void qkv256(const unsigned short* __restrict__ x1, const unsigned short* __restrict__ x2,
            const unsigned short* __restrict__ W6,
            const float* bq1, const float* bk1, const float* bv1,
            const float* bq2, const float* bk2, const float* bv2,
            unsigned short* q1, unsigned short* k1, unsigned short* v1T,
            unsigned short* q2, unsigned short* k2, unsigned short* v2T)
{
  const int g = blockIdx.z;
  const unsigned short* A = (g < 3) ? x1 : x2;
  const unsigned short* W = W6 + (size_t)g * (DIM * DIM);
  const float* bias = (g == 0) ? bq1 : (g == 1) ? bk1 : (g == 2) ? bv1
                    : (g == 3) ? bq2 : (g == 4) ? bk2 : bv2;
  unsigned short* out = (g == 0) ? q1 : (g == 1) ? k1 : (g == 2) ? v1T
                      : (g == 3) ? q2 : (g == 4) ? k2 : v2T;
  const bool vT = (g == 2 || g == 5);

  f32x4 acc[8][4];
  core256(A, DIM, W, DIM, DIM, blockIdx.y, blockIdx.x, acc);

  const int t = threadIdx.x, w = t >> 6, l = t & 63;
  const int wr = w >> 2, wc = w & 3;
  const int r4 = (l >> 4) * 4, c = l & 15;
  const int row0 = blockIdx.y * 256 + wr * 128;
  const int col0 = blockIdx.x * 256 + wc * 64;

  float bias_v[4];
#pragma unroll
  for (int nf = 0; nf < 4; ++nf) bias_v[nf] = bias[col0 + nf*16 + c];

  if (!vT) {
#pragma unroll
    for (int mf = 0; mf < 8; ++mf)
#pragma unroll
      for (int nf = 0; nf < 4; ++nf)
#pragma unroll
        for (int i = 0; i < 4; ++i)
          out[(size_t)(row0 + mf*16 + r4 + i) * DIM + col0 + nf*16 + c] =
              f2bf(acc[mf][nf][i] + bias_v[nf]);
  } else {
#pragma unroll
    for (int mf = 0; mf < 8; ++mf)
#pragma unroll
      for (int nf = 0; nf < 4; ++nf) {
        short4v pk;
#pragma unroll
        for (int i = 0; i < 4; ++i) pk[i] = (short)f2bf(acc[mf][nf][i] + bias_v[nf]);
        *(short4v*)(out + (size_t)(col0 + nf*16 + c) * NTOK + row0 + mf*16 + r4) = pk;
      }
  }
}

// =====================================================================
// old 128x128 2-phase core — kept for PV (split-K) only
// =====================================================================
DEVINL void gemm_core(const unsigned short* __restrict__ A, int lda,
                      const unsigned short* __restrict__ B, int ldb,
                      int kb, int klen, int brow, int bcol,
                      f32x4 acc[4][4], unsigned short* lds)
{
  const int t = threadIdx.x;
  const int wave = t >> 6, lane = t & 63;
  const int wr = wave >> 1, wc = wave & 1;
  const int frow = lane & 15;
  const int kq = (lane >> 4) * 8;
  const int sr = lane >> 2;
  const int sc = (lane & 3) * 8;

  const unsigned short* Arow = A + (size_t)(brow * BM) * lda + kb;
  const unsigned short* Brow = B + (size_t)(bcol * BN) * ldb + kb;

  unsigned short* As0 = lds;
  unsigned short* Bs0 = lds + BM * BK;
  unsigned short* As1 = lds + 2 * BM * BK;
  unsigned short* Bs1 = lds + 3 * BM * BK;

#define STAGE(Asb, Bsb, k0)                                                   \
  {                                                                           \
    _Pragma("unroll")                                                         \
    for (int r = 0; r < 2; ++r) {                                             \
      const int rb = (r * 4 + wave) * 16;                                     \
      gll16(Arow + (size_t)(rb + sr) * lda + (k0) + sc, (Asb) + rb * BK);     \
      gll16(Brow + (size_t)(rb + sr) * ldb + (k0) + sc, (Bsb) + rb * BK);     \
    }                                                                         \
  }

  STAGE(As0, Bs0, 0);
  asm volatile("s_waitcnt vmcnt(0)" ::: "memory");
  __syncthreads();

  const int nt = klen / BK;
  for (int tile = 0; tile < nt; ++tile) {
    unsigned short* Ac = (tile & 1) ? As1 : As0;
    unsigned short* Bc = (tile & 1) ? Bs1 : Bs0;
    unsigned short* An = (tile & 1) ? As0 : As1;
    unsigned short* Bn = (tile & 1) ? Bs0 : Bs1;

    if (tile + 1 < nt) STAGE(An, Bn, (tile + 1) * BK);

    bf16x8 af[4], bfv[4];
#pragma unroll
    for (int m = 0; m < 4; ++m)
      af[m] = *(const bf16x8*)(Ac + (wr * 64 + m * 16 + frow) * BK + kq);
#pragma unroll
    for (int n = 0; n < 4; ++n)
      bfv[n] = *(const bf16x8*)(Bc + (wc * 64 + n * 16 + frow) * BK + kq);

#pragma unroll
    for (int m = 0; m < 4; ++m)
#pragma unroll
      for (int n = 0; n < 4; ++n)
        acc[m][n] = __builtin_amdgcn_mfma_f32_16x16x32_bf16(af[m], bfv[n], acc[m][n], 0, 0, 0);

    asm volatile("s_waitcnt vmcnt(0)" ::: "memory");
    __syncthreads();
  }
#undef STAGE
}

// PV GEMM: out = f32(acc), split-K via blockIdx.z (z>0 -> Part)
__global__ __launch_bounds__(256, 4)
void gemm_nt_f32(const unsigned short* __restrict__ A, int lda,
                 const unsigned short* __restrict__ B, int ldb,
                 float* __restrict__ Out, float* __restrict__ Part,
                 int klen, int ldo)
{
  __shared__ unsigned short lds[4 * BM * BK];
  f32x4 acc[4][4];
#pragma unroll
  for (int m = 0; m < 4; ++m)
#pragma unroll
    for (int n = 0; n < 4; ++n) {
      f32x4 z = {0.f, 0.f, 0.f, 0.f};
      acc[m][n] = z;
    }
  gemm_core(A, lda, B, ldb, blockIdx.z * klen, klen, blockIdx.y, blockIdx.x, acc, lds);

  float* dst = (blockIdx.z == 0) ? Out : Part;
  const int t = threadIdx.x, wave = t >> 6, lane = t & 63;
  const int wr = wave >> 1, wc = wave & 1;
  const int rr = (lane >> 4) * 4, cc = lane & 15;
#pragma unroll
  for (int m = 0; m < 4; ++m) {
    const int row0 = blockIdx.y * BM + wr * 64 + m * 16 + rr;
#pragma unroll
    for (int n = 0; n < 4; ++n) {
      const int col = blockIdx.x * BN + wc * 64 + n * 16 + cc;
#pragma unroll
      for (int i = 0; i < 4; ++i)
        dst[(size_t)(row0 + i) * ldo + col] = acc[m][n][i];
    }
  }
}

__global__ __launch_bounds__(256)
void add_partial(float* __restrict__ out, const float* __restrict__ part, int n4)
{
  const int i = blockIdx.x * 256 + threadIdx.x;
  if (i < n4) {
    float4v a = ((const float4v*)out)[i];
    float4v b = ((const float4v*)part)[i];
#pragma unroll
    for (int j = 0; j < 4; ++j) a[j] += b[j];
    ((float4v*)out)[i] = a;
  }
}

// ---------- row softmax, in place on bf16 [4096 x 4096] ----------
__global__ __launch_bounds__(256)
void softmax_inplace(unsigned short* __restrict__ S)
{
  const int row = blockIdx.x;
  unsigned short* r = S + (size_t)row * NTOK;
  const int t = threadIdx.x, wave = t >> 6, lane = t & 63;
  __shared__ float red[4];

  bf16x8 d0 = *(const bf16x8*)(r + t * 8);
  bf16x8 d1 = *(const bf16x8*)(r + 2048 + t * 8);
  float v[16];
  {
    const unsigned short* p0 = (const unsigned short*)&d0;
    const unsigned short* p1 = (const unsigned short*)&d1;
#pragma unroll
    for (int j = 0; j < 8; ++j) { v[j] = bf2f(p0[j]); v[8 + j] = bf2f(p1[j]); }
  }
  float mx = v[0];
#pragma unroll
  for (int j = 1; j < 16; ++j) mx = fmaxf(mx, v[j]);
#pragma unroll
  for (int o = 32; o > 0; o >>= 1) mx = fmaxf(mx, __shfl_xor(mx, o));
  if (lane == 0) red[wave] = mx;
  __syncthreads();
  mx = fmaxf(fmaxf(red[0], red[1]), fmaxf(red[2], red[3]));

  float s = 0.f;
#pragma unroll
  for (int j = 0; j < 16; ++j) { v[j] = __expf(v[j] - mx); s += v[j]; }
#pragma unroll
  for (int o = 32; o > 0; o >>= 1) s += __shfl_xor(s, o);
  __syncthreads();
  if (lane == 0) red[wave] = s;
  __syncthreads();
  s = red[0] + red[1] + red[2] + red[3];
  const float inv = 1.0f / s;

  unsigned short o0[8], o1[8];
#pragma unroll
  for (int j = 0; j < 8; ++j) { o0[j] = f2bf(v[j] * inv); o1[j] = f2bf(v[8 + j] * inv); }
  *(bf16x8*)(r + t * 8)        = *(const bf16x8*)o0;
  *(bf16x8*)(r + 2048 + t * 8) = *(const bf16x8*)o1;
}

// ---------- fp32 -> bf16 converters ----------
__global__ __launch_bounds__(256)
void cvt2(const float* __restrict__ a, const float* __restrict__ b,
          unsigned short* __restrict__ oa, unsigned short* __restrict__ ob)
{
  const float* in = blockIdx.y ? b : a;
  unsigned short* out = blockIdx.y ? ob : oa;
  const size_t i = ((size_t)blockIdx.x * 256 + threadIdx.x) * 4;
  float4v x = *(const float4v*)(in + i);
  short4v o;
#pragma unroll
  for (int j = 0; j < 4; ++j) o[j] = (short)f2bf(x[j]);
  *(short4v*)(out + i) = o;
}

__global__ __launch_bounds__(256)
void cvt_w(const float* w0, const float* w1, const float* w2,
           const float* w3, const float* w4, const float* w5,
           unsigned short* __restrict__ W6)
{
  const float* srcs[6] = {w0, w1, w2, w3, w4, w5};
  const float* in = srcs[blockIdx.y];
  unsigned short* out = W6 + (size_t)blockIdx.y * (DIM * DIM);
  const size_t i = ((size_t)blockIdx.x * 256 + threadIdx.x) * 4;
  float4v x = *(const float4v*)(in + i);
  short4v o;
#pragma unroll
  for (int j = 0; j < 4; ++j) o[j] = (short)f2bf(x[j]);
  *(short4v*)(out + i) = o;
}

// ---------- host launcher ----------
extern "C" void kernel_launch(void* const* d_in, const int* in_sizes, int n_in,
                              void* d_out, int out_size, void* d_ws, size_t ws_size,
                              hipStream_t stream)
{
  const float* x1  = (const float*)d_in[0];
  const float* x2  = (const float*)d_in[1];
  const float* Wq1 = (const float*)d_in[2];  const float* bq1 = (const float*)d_in[3];
  const float* Wk1 = (const float*)d_in[4];  const float* bk1 = (const float*)d_in[5];
  const float* Wv1 = (const float*)d_in[6];  const float* bv1 = (const float*)d_in[7];
  const float* Wq2 = (const float*)d_in[8];  const float* bq2 = (const float*)d_in[9];
  const float* Wk2 = (const float*)d_in[10]; const float* bk2 = (const float*)d_in[11];
  const float* Wv2 = (const float*)d_in[12]; const float* bv2 = (const float*)d_in[13];
  float* out = (float*)d_out;

  // ws layout (ushort elems): x1b(4M) x2b(4M) W6(6M) q1 k1 v1T q2 k2 v2T (4M each) S(16M)
  // P1 (fp32 PV partial, 16MB) aliases x1b+x2b (dead after qkv256).
  unsigned short* ws  = (unsigned short*)d_ws;
  const size_t NTD = (size_t)NTOK * DIM;
  unsigned short* x1b = ws;
  unsigned short* x2b = x1b + NTD;
  unsigned short* W6  = x2b + NTD;
  unsigned short* q1  = W6 + 6 * (size_t)(DIM * DIM);
  unsigned short* k1  = q1 + NTD;
  unsigned short* v1T = k1 + NTD;
  unsigned short* q2  = v1T + NTD;
  unsigned short* k2  = q2 + NTD;
  unsigned short* v2T = k2 + NTD;
  unsigned short* S   = v2T + NTD;
  float* P1 = (float*)ws;

  const dim3 blk(256);
  cvt2 <<<dim3(NTD / 1024, 2), blk, 0, stream>>>(x1, x2, x1b, x2b);
  cvt_w<<<dim3((DIM * DIM) / 1024, 6), blk, 0, stream>>>(Wq1, Wk1, Wv1, Wq2, Wk2, Wv2, W6);

  qkv256<<<dim3(DIM / 256, NTOK / 256, 6), dim3(512), 0, stream>>>(
      x1b, x2b, W6, bq1, bk1, bv1, bq2, bk2, bv2, q1, k1, v1T, q2, k2, v2T);

  const float scale = 0.03125f;  // 1/sqrt(1024)
  const int KH = NTOK / 2;

  // context1 = softmax(q2 k1^T / 32) @ v1
  gemm256_scores<<<dim3(NTOK / 256, NTOK / 256), dim3(512), 0, stream>>>(q2, k1, S, scale);
  softmax_inplace<<<dim3(NTOK), blk, 0, stream>>>(S);
  gemm_nt_f32<<<dim3(DIM / BN, NTOK / BM, 2), blk, 0, stream>>>(S, NTOK, v1T, NTOK, out, P1, KH, DIM);
  add_partial<<<dim3((NTD / 4 + 255) / 256), blk, 0, stream>>>(out, P1, NTD / 4);

  // context2 = softmax(q1 k2^T / 32) @ v2
  gemm256_scores<<<dim3(NTOK / 256, NTOK / 256), dim3(512), 0, stream>>>(q1, k2, S, scale);
  softmax_inplace<<<dim3(NTOK), blk, 0, stream>>>(S);
  gemm_nt_f32<<<dim3(DIM / BN, NTOK / BM, 2), blk, 0, stream>>>(S, NTOK, v2T, NTOK, out + NTD, P1, KH, DIM);
  add_partial<<<dim3((NTD / 4 + 255) / 256), blk, 0, stream>>>(out + NTD, P1, NTD / 4);
}

// Round 4
// 260.953 us; speedup vs baseline: 1.3343x; 1.1033x over previous
//
#include <hip/hip_runtime.h>
#include <hip/hip_bf16.h>
#include <cstdint>
#include <cstddef>

#define DEVINL __device__ __forceinline__

typedef __attribute__((ext_vector_type(4))) float   f32x4;
typedef __bf16 bf16x8 __attribute__((ext_vector_type(8)));
typedef __attribute__((ext_vector_type(4))) short   short4v;
typedef __attribute__((ext_vector_type(4))) float   float4v;

static constexpr int DIM = 1024;
static constexpr int NTOK = 4096;

// ---------- scalar helpers ----------
DEVINL unsigned short f2bf(float f) {
  unsigned u = __float_as_uint(f);
  u += 0x7FFF + ((u >> 16) & 1);
  return (unsigned short)(u >> 16);
}
DEVINL float bf2f(unsigned short s) {
  return __uint_as_float(((unsigned)s) << 16);
}

DEVINL void gll16(const void* g, void* l) {
  __builtin_amdgcn_global_load_lds(
      (const __attribute__((address_space(1))) void*)g,
      (__attribute__((address_space(3))) void*)l, 16, 0, 0);
}

// =====================================================================
// 256x256xK 8-wave core, v2 schedule: 2 barriers + 2 counted vmcnt waits
// per K-tile (BK=64); phases p2/p3 free-run (no sync) for cross-wave
// MFMA/ds_read overlap. A,B K-major (NT). T2 swizzle (verified 0 bank
// conflicts). LDS 128 KB: [A0|B0|A1|B1] halves of 2 tile double-buffers.
//
// Ledger (per-wave vmcnt, 2 gll per STpair, 4 ops per phase-group):
//  p0(kt): VMW4 drains {A0,B0}(kt) [staged p0(kt-1)]; BARR; stage {A0,B0}(kt+1)
//  p1(kt): VMW4 drains {A1,B1}(kt) [staged p1(kt-1)]; BARR; stage {A1,B1}(kt+1)
//  p2,p3: reads of B1/A0 already verified at p1/p0; no sync.
// Stage-overwrite safety: region staged at p_i(kt) was last ds_read at a
// phase whose LGW precedes the p_i barrier for all waves (collective).
// =====================================================================
DEVINL void core256(const unsigned short* __restrict__ A, int lda,
                    const unsigned short* __restrict__ B, int ldb,
                    int K, int brow, int bcol, f32x4 acc[8][4])
{
  __shared__ unsigned short lds[65536];   // 128 KB
  const int t = threadIdx.x;
  const int w = t >> 6, l = t & 63;
  const int wr = w >> 2, wc = w & 3;
  const int srow = l >> 3;
  const int scol = ((l & 7) ^ srow) << 3;                    // inverse-swizzled source col
  const int l15 = l & 15;
  const int cs0 = (((l >> 4) << 3)       ^ ((l & 7) << 3));  // swizzled read col, ks=0
  const int cs1 = ((32 + ((l >> 4) << 3)) ^ ((l & 7) << 3)); // ks=1

  const unsigned short* aL = A + (size_t)(brow * 256 + srow) * lda + scol;
  const unsigned short* bL = B + (size_t)(bcol * 256 + srow) * ldb + scol;

#pragma unroll
  for (int m = 0; m < 8; ++m)
#pragma unroll
    for (int n = 0; n < 4; ++n) {
      f32x4 z = {0.f, 0.f, 0.f, 0.f};
      acc[m][n] = z;
    }

#define STA_(Sbase, h, r, kt)                                                  \
  gll16(aL + (size_t)((r)*128 + (h)*64 + (w << 3)) * lda + (size_t)(kt)*64,    \
        (Sbase) + ((r)*128 + (h)*64 + (w << 3)) * 64)
#define STB_(Sbase, h, r, kt)                                                  \
  { const int g16_ = w + (r)*8;                                                \
    const int r0_ = (g16_ >> 2)*64 + (h)*32 + (g16_ & 3)*8;                    \
    gll16(bL + (size_t)r0_ * ldb + (size_t)(kt)*64, (Sbase) + r0_ * 64); }
#define LDA_(Abase, mh)                                                        \
  _Pragma("unroll")                                                            \
  for (int m4 = 0; m4 < 4; ++m4) {                                             \
    const unsigned short* p_ = (Abase) + (wr*128 + (mh)*64 + m4*16 + l15)*64;  \
    af[m4][0] = *(const bf16x8*)(p_ + cs0);                                    \
    af[m4][1] = *(const bf16x8*)(p_ + cs1);                                    \
  }
#define LDB_(Bbase, nh)                                                        \
  _Pragma("unroll")                                                            \
  for (int n2 = 0; n2 < 2; ++n2) {                                             \
    const unsigned short* p_ = (Bbase) + (wc*64 + (nh)*32 + n2*16 + l15)*64;   \
    bfr[n2][0] = *(const bf16x8*)(p_ + cs0);                                   \
    bfr[n2][1] = *(const bf16x8*)(p_ + cs1);                                   \
  }
#define MF_(mh, nh)                                                            \
  __builtin_amdgcn_s_setprio(1);                                               \
  _Pragma("unroll")                                                            \
  for (int m4 = 0; m4 < 4; ++m4)                                               \
  _Pragma("unroll")                                                            \
  for (int n2 = 0; n2 < 2; ++n2) {                                             \
    f32x4 c_ = acc[(mh)*4 + m4][(nh)*2 + n2];                                  \
    c_ = __builtin_amdgcn_mfma_f32_16x16x32_bf16(af[m4][0], bfr[n2][0], c_, 0,0,0); \
    c_ = __builtin_amdgcn_mfma_f32_16x16x32_bf16(af[m4][1], bfr[n2][1], c_, 0,0,0); \
    acc[(mh)*4 + m4][(nh)*2 + n2] = c_;                                        \
  }                                                                            \
  __builtin_amdgcn_s_setprio(0);
#define VMW4() asm volatile("s_waitcnt vmcnt(4)" ::: "memory")
#define VMW0() asm volatile("s_waitcnt vmcnt(0)" ::: "memory")
#define LGW()  do { asm volatile("s_waitcnt lgkmcnt(0)" ::: "memory");         \
                    __builtin_amdgcn_sched_barrier(0); } while (0)
#define BARR() do { __builtin_amdgcn_s_barrier();                              \
                    asm volatile("" ::: "memory"); } while (0)

  // prologue: tile 0, groups [A0,B0] then [A1,B1]
  {
    unsigned short* S0  = lds;
    unsigned short* S0b = lds + 16384;
    STA_(S0, 0, 0, 0); STA_(S0, 0, 1, 0); STB_(S0b, 0, 0, 0); STB_(S0b, 0, 1, 0);
    STA_(S0, 1, 0, 0); STA_(S0, 1, 1, 0); STB_(S0b, 1, 0, 0); STB_(S0b, 1, 1, 0);
  }

  bf16x8 af[4][2], bfr[2][2];
  const int NT = K >> 6;
  for (int kt = 0; kt < NT - 1; ++kt) {
    const unsigned short* Ab = lds + (kt & 1) * 32768;
    const unsigned short* Bb = Ab + 16384;
    unsigned short* Sa = lds + ((kt & 1) ^ 1) * 32768;
    unsigned short* Sb = Sa + 16384;

    // p0: quadrant (m0,n0)
    VMW4(); BARR();
    STA_(Sa, 0, 0, kt + 1); STA_(Sa, 0, 1, kt + 1);
    STB_(Sb, 0, 0, kt + 1); STB_(Sb, 0, 1, kt + 1);
    LDA_(Ab, 0); LDB_(Bb, 0);
    LGW(); MF_(0, 0);

    // p1: quadrant (m1,n0)
    VMW4(); BARR();
    STA_(Sa, 1, 0, kt + 1); STA_(Sa, 1, 1, kt + 1);
    STB_(Sb, 1, 0, kt + 1); STB_(Sb, 1, 1, kt + 1);
    LDA_(Ab, 1);
    LGW(); MF_(1, 0);

    // p2: quadrant (m1,n1) — free-running (B1 verified at p1's wait+barrier)
    LDB_(Bb, 1);
    LGW(); MF_(1, 1);

    // p3: quadrant (m0,n1) — free-running (A0 verified at p0)
    LDA_(Ab, 0);
    LGW(); MF_(0, 1);
  }

  // peeled last tile: no staging; drain 4 -> 0
  {
    const int kt = NT - 1;
    const unsigned short* Ab = lds + (kt & 1) * 32768;
    const unsigned short* Bb = Ab + 16384;
    VMW4(); BARR();
    LDA_(Ab, 0); LDB_(Bb, 0);
    LGW(); MF_(0, 0);
    VMW0(); BARR();
    LDA_(Ab, 1);
    LGW(); MF_(1, 0);
    LDB_(Bb, 1);
    LGW(); MF_(1, 1);
    LDA_(Ab, 0);
    LGW(); MF_(0, 1);
  }
#undef STA_
#undef STB_
#undef LDA_
#undef LDB_
#undef MF_
#undef VMW4
#undef VMW0
#undef LGW
#undef BARR
}

// ---------- scores: S = bf16( (A B^T) * scale ), [4096 x 4096] ----------
__global__ __launch_bounds__(512, 2)
void gemm256_scores(const unsigned short* __restrict__ A,
                    const unsigned short* __restrict__ B,
                    unsigned short* __restrict__ S, float scale)
{
  f32x4 acc[8][4];
  core256(A, DIM, B, DIM, DIM, blockIdx.y, blockIdx.x, acc);

  const int t = threadIdx.x, w = t >> 6, l = t & 63;
  const int wr = w >> 2, wc = w & 3;
  const int r4 = (l >> 4) * 4, c = l & 15;
  const int row0 = blockIdx.y * 256 + wr * 128;
  const int col0 = blockIdx.x * 256 + wc * 64;
#pragma unroll
  for (int mf = 0; mf < 8; ++mf)
#pragma unroll
    for (int nf = 0; nf < 4; ++nf)
#pragma unroll
      for (int i = 0; i < 4; ++i)
        S[(size_t)(row0 + mf*16 + r4 + i) * NTOK + col0 + nf*16 + c] =
            f2bf(acc[mf][nf][i] * scale);
}

// ---------- merged QKV: grid.z = 6; v outputs transposed ----------
__global__ __launch_bounds__(512, 2)
void qkv256(const unsigned short* __restrict__ x1, const unsigned short* __restrict__ x2,
            const unsigned short* __restrict__ W6,
            const float* bq1, const float* bk1, const float* bv1,
            const float* bq2, const float* bk2, const float* bv2,
            unsigned short* q1, unsigned short* k1, unsigned short* v1T,
            unsigned short* q2, unsigned short* k2, unsigned short* v2T)
{
  const int g = blockIdx.z;
  const unsigned short* A = (g < 3) ? x1 : x2;
  const unsigned short* W = W6 + (size_t)g * (DIM * DIM);
  const float* bias = (g == 0) ? bq1 : (g == 1) ? bk1 : (g == 2) ? bv1
                    : (g == 3) ? bq2 : (g == 4) ? bk2 : bv2;
  unsigned short* out = (g == 0) ? q1 : (g == 1) ? k1 : (g == 2) ? v1T
                      : (g == 3) ? q2 : (g == 4) ? k2 : v2T;
  const bool vT = (g == 2 || g == 5);

  f32x4 acc[8][4];
  core256(A, DIM, W, DIM, DIM, blockIdx.y, blockIdx.x, acc);

  const int t = threadIdx.x, w = t >> 6, l = t & 63;
  const int wr = w >> 2, wc = w & 3;
  const int r4 = (l >> 4) * 4, c = l & 15;
  const int row0 = blockIdx.y * 256 + wr * 128;
  const int col0 = blockIdx.x * 256 + wc * 64;

  float bias_v[4];
#pragma unroll
  for (int nf = 0; nf < 4; ++nf) bias_v[nf] = bias[col0 + nf*16 + c];

  if (!vT) {
#pragma unroll
    for (int mf = 0; mf < 8; ++mf)
#pragma unroll
      for (int nf = 0; nf < 4; ++nf)
#pragma unroll
        for (int i = 0; i < 4; ++i)
          out[(size_t)(row0 + mf*16 + r4 + i) * DIM + col0 + nf*16 + c] =
              f2bf(acc[mf][nf][i] + bias_v[nf]);
  } else {
#pragma unroll
    for (int mf = 0; mf < 8; ++mf)
#pragma unroll
      for (int nf = 0; nf < 4; ++nf) {
        short4v pk;
#pragma unroll
        for (int i = 0; i < 4; ++i) pk[i] = (short)f2bf(acc[mf][nf][i] + bias_v[nf]);
        *(short4v*)(out + (size_t)(col0 + nf*16 + c) * NTOK + row0 + mf*16 + r4) = pk;
      }
  }
}

// ---------- fused PV: C[4096 x 2048] = [P1@V1 | P2@V2], split-K=2 ----------
// A = S1 (cols 0-1023) or S2 (cols 1024-2047), lda=4096; B = vTcat [2048 x 4096].
// z=0 -> final dst (out, split 2 halves), z=1 -> fp32 partial P [4096 x 2048].
__global__ __launch_bounds__(512, 2)
void pv_fused(const unsigned short* __restrict__ S1,
              const unsigned short* __restrict__ S2,
              const unsigned short* __restrict__ vTcat,
              float* __restrict__ out, float* __restrict__ P)
{
  const int bx = blockIdx.x, by = blockIdx.y, z = blockIdx.z;
  const unsigned short* A = ((bx < 4) ? S1 : S2) + (size_t)z * 2048;
  const unsigned short* B = vTcat + (size_t)z * 2048;

  f32x4 acc[8][4];
  core256(A, NTOK, B, NTOK, 2048, by, bx, acc);

  const int t = threadIdx.x, w = t >> 6, l = t & 63;
  const int wr = w >> 2, wc = w & 3;
  const int r4 = (l >> 4) * 4, c = l & 15;
  const int row0 = by * 256 + wr * 128;
  const int col0 = bx * 256 + wc * 64;

#pragma unroll
  for (int mf = 0; mf < 8; ++mf)
#pragma unroll
    for (int nf = 0; nf < 4; ++nf)
#pragma unroll
      for (int i = 0; i < 4; ++i) {
        const int r = row0 + mf*16 + r4 + i;
        const int cg = col0 + nf*16 + c;
        if (z) {
          P[(size_t)r * 2048 + cg] = acc[mf][nf][i];
        } else {
          float* dst = (cg < 1024) ? (out + (size_t)r * 1024 + cg)
                                   : (out + 4194304 + (size_t)r * 1024 + (cg - 1024));
          *dst = acc[mf][nf][i];
        }
      }
}

// out(+4M) += P, remapping [4096 x 2048] partial onto the two context halves
__global__ __launch_bounds__(256)
void add_pv(float* __restrict__ out, const float* __restrict__ P)
{
  const int idx = blockIdx.x * 256 + threadIdx.x;   // 2M threads, 4 floats each
  const int r  = idx >> 9;
  const int c4 = (idx & 511) << 2;
  const float4v p = *(const float4v*)(P + (size_t)r * 2048 + c4);
  float* dst = (c4 < 1024) ? (out + (size_t)r * 1024 + c4)
                           : (out + 4194304 + (size_t)r * 1024 + (c4 - 1024));
  float4v a = *(const float4v*)dst;
#pragma unroll
  for (int j = 0; j < 4; ++j) a[j] += p[j];
  *(float4v*)dst = a;
}

// ---------- row softmax, in place on bf16 [4096 x 4096] ----------
__global__ __launch_bounds__(256)
void softmax_inplace(unsigned short* __restrict__ S)
{
  const int row = blockIdx.x;
  unsigned short* r = S + (size_t)row * NTOK;
  const int t = threadIdx.x, wave = t >> 6, lane = t & 63;
  __shared__ float red[4];

  bf16x8 d0 = *(const bf16x8*)(r + t * 8);
  bf16x8 d1 = *(const bf16x8*)(r + 2048 + t * 8);
  float v[16];
  {
    const unsigned short* p0 = (const unsigned short*)&d0;
    const unsigned short* p1 = (const unsigned short*)&d1;
#pragma unroll
    for (int j = 0; j < 8; ++j) { v[j] = bf2f(p0[j]); v[8 + j] = bf2f(p1[j]); }
  }
  float mx = v[0];
#pragma unroll
  for (int j = 1; j < 16; ++j) mx = fmaxf(mx, v[j]);
#pragma unroll
  for (int o = 32; o > 0; o >>= 1) mx = fmaxf(mx, __shfl_xor(mx, o));
  if (lane == 0) red[wave] = mx;
  __syncthreads();
  mx = fmaxf(fmaxf(red[0], red[1]), fmaxf(red[2], red[3]));

  float s = 0.f;
#pragma unroll
  for (int j = 0; j < 16; ++j) { v[j] = __expf(v[j] - mx); s += v[j]; }
#pragma unroll
  for (int o = 32; o > 0; o >>= 1) s += __shfl_xor(s, o);
  __syncthreads();
  if (lane == 0) red[wave] = s;
  __syncthreads();
  s = red[0] + red[1] + red[2] + red[3];
  const float inv = 1.0f / s;

  unsigned short o0[8], o1[8];
#pragma unroll
  for (int j = 0; j < 8; ++j) { o0[j] = f2bf(v[j] * inv); o1[j] = f2bf(v[8 + j] * inv); }
  *(bf16x8*)(r + t * 8)        = *(const bf16x8*)o0;
  *(bf16x8*)(r + 2048 + t * 8) = *(const bf16x8*)o1;
}

// ---------- fp32 -> bf16 converters ----------
__global__ __launch_bounds__(256)
void cvt2(const float* __restrict__ a, const float* __restrict__ b,
          unsigned short* __restrict__ oa, unsigned short* __restrict__ ob)
{
  const float* in = blockIdx.y ? b : a;
  unsigned short* out = blockIdx.y ? ob : oa;
  const size_t i = ((size_t)blockIdx.x * 256 + threadIdx.x) * 4;
  float4v x = *(const float4v*)(in + i);
  short4v o;
#pragma unroll
  for (int j = 0; j < 4; ++j) o[j] = (short)f2bf(x[j]);
  *(short4v*)(out + i) = o;
}

__global__ __launch_bounds__(256)
void cvt_w(const float* w0, const float* w1, const float* w2,
           const float* w3, const float* w4, const float* w5,
           unsigned short* __restrict__ W6)
{
  const float* srcs[6] = {w0, w1, w2, w3, w4, w5};
  const float* in = srcs[blockIdx.y];
  unsigned short* out = W6 + (size_t)blockIdx.y * (DIM * DIM);
  const size_t i = ((size_t)blockIdx.x * 256 + threadIdx.x) * 4;
  float4v x = *(const float4v*)(in + i);
  short4v o;
#pragma unroll
  for (int j = 0; j < 4; ++j) o[j] = (short)f2bf(x[j]);
  *(short4v*)(out + i) = o;
}

// ---------- host launcher ----------
extern "C" void kernel_launch(void* const* d_in, const int* in_sizes, int n_in,
                              void* d_out, int out_size, void* d_ws, size_t ws_size,
                              hipStream_t stream)
{
  const float* x1  = (const float*)d_in[0];
  const float* x2  = (const float*)d_in[1];
  const float* Wq1 = (const float*)d_in[2];  const float* bq1 = (const float*)d_in[3];
  const float* Wk1 = (const float*)d_in[4];  const float* bk1 = (const float*)d_in[5];
  const float* Wv1 = (const float*)d_in[6];  const float* bv1 = (const float*)d_in[7];
  const float* Wq2 = (const float*)d_in[8];  const float* bq2 = (const float*)d_in[9];
  const float* Wk2 = (const float*)d_in[10]; const float* bk2 = (const float*)d_in[11];
  const float* Wv2 = (const float*)d_in[12]; const float* bv2 = (const float*)d_in[13];
  float* out = (float*)d_out;

  // ws layout (ushort units), 112 MiB high-water:
  //  [0,16M):    R0 = x1b(4M) x2b(4M) W6(6M) pad -> later S1 [4096x4096]
  //  [16M,32M):  S2
  //  [32M,48M):  q1 k1 q2 k2 (4M each)           -> later P (fp32 partial, 32 MB)
  //  [48M,56M):  v1T v2T (vTcat, [2048 x 4096])
  unsigned short* ws  = (unsigned short*)d_ws;
  const size_t NTD = (size_t)NTOK * DIM;           // 4M elems
  const size_t SM  = (size_t)NTOK * NTOK;          // 16M elems
  unsigned short* x1b = ws;
  unsigned short* x2b = x1b + NTD;
  unsigned short* W6  = x2b + NTD;
  unsigned short* S1  = ws;
  unsigned short* S2  = ws + SM;
  unsigned short* q1  = ws + 2 * SM;
  unsigned short* k1  = q1 + NTD;
  unsigned short* q2  = k1 + NTD;
  unsigned short* k2  = q2 + NTD;
  unsigned short* vT  = k2 + NTD;                  // v1T followed by v2T
  unsigned short* v1T = vT;
  unsigned short* v2T = vT + NTD;
  float* P = (float*)q1;                           // 32 MB partial over dead q/k

  const dim3 blk(256);
  cvt2 <<<dim3(NTD / 1024, 2), blk, 0, stream>>>(x1, x2, x1b, x2b);
  cvt_w<<<dim3((DIM * DIM) / 1024, 6), blk, 0, stream>>>(Wq1, Wk1, Wv1, Wq2, Wk2, Wv2, W6);

  qkv256<<<dim3(DIM / 256, NTOK / 256, 6), dim3(512), 0, stream>>>(
      x1b, x2b, W6, bq1, bk1, bv1, bq2, bk2, bv2, q1, k1, v1T, q2, k2, v2T);

  const float scale = 0.03125f;  // 1/sqrt(1024)

  // scores + softmax (S1 overwrites dead x/W region)
  gemm256_scores<<<dim3(NTOK / 256, NTOK / 256), dim3(512), 0, stream>>>(q2, k1, S1, scale);
  softmax_inplace<<<dim3(NTOK), blk, 0, stream>>>(S1);
  gemm256_scores<<<dim3(NTOK / 256, NTOK / 256), dim3(512), 0, stream>>>(q1, k2, S2, scale);
  softmax_inplace<<<dim3(NTOK), blk, 0, stream>>>(S2);

  // fused PV over [v1T; v2T], split-K=2 (q/k region now dead -> P)
  pv_fused<<<dim3(8, NTOK / 256, 2), dim3(512), 0, stream>>>(S1, S2, vT, out, P);
  add_pv<<<dim3(8192), blk, 0, stream>>>(out, P);
}